// Round 1
// baseline (176.243 us; speedup 1.0000x reference)
//
#include <hip/hip_runtime.h>
#include <hip/hip_bf16.h>

typedef __attribute__((ext_vector_type(8))) short short8;
typedef __attribute__((ext_vector_type(4))) short bf16x4;
typedef __attribute__((ext_vector_type(4))) float floatx4;

#define MFMA16(a, b, c) __builtin_amdgcn_mfma_f32_16x16x32_bf16((a), (b), (c), 0, 0, 0)

#if defined(__HIP_DEVICE_COMPILE__)
  #if __has_builtin(__builtin_amdgcn_mfma_f32_16x16x16bf16_1k)
    #define MFMA_PV(a, b, c) __builtin_amdgcn_mfma_f32_16x16x16bf16_1k((a), (b), (c), 0, 0, 0)
  #elif __has_builtin(__builtin_amdgcn_mfma_f32_16x16x16_bf16)
    #define MFMA_PV(a, b, c) __builtin_amdgcn_mfma_f32_16x16x16_bf16((a), (b), (c), 0, 0, 0)
  #else
    #error "no 16x16x16 bf16 MFMA builtin found on device pass"
  #endif
#else
  #define MFMA_PV(a, b, c) (c)   // host pass: never executed
#endif

#if defined(__HIP_DEVICE_COMPILE__) && __has_builtin(__builtin_amdgcn_global_load_lds)
  #define HAVE_GLOAD 1
#else
  #define HAVE_GLOAD 0
#endif

#define SEQ    2048
#define DIMM   1024
#define HEADS  16
#define DHEAD  64
#define ROWS   4096      // b*n = 2*2048
// fixed-max softmax: p = exp2(s*K1 + K2), K1 = 0.125*log2(e), K2 = -24*log2(e)
#define K1 0.18033688011112043f
#define K2 (-34.62468098133512f)

// async global(16B/lane) -> LDS (wave-uniform base + lane*16)
__device__ __forceinline__ void gload16(const void* g, void* l) {
#if HAVE_GLOAD
    __builtin_amdgcn_global_load_lds(
        (const __attribute__((address_space(1))) void*)g,
        (__attribute__((address_space(3))) void*)l, 16, 0, 0);
#else
    (void)g; (void)l;   // replaced by reg-staged path in stage()
#endif
}

// ---------------------------------------------------------------------------
// Prep kernels (unchanged).
// ---------------------------------------------------------------------------
__global__ void cvt_bf16_kernel(const float* __restrict__ src,
                                __hip_bfloat16* __restrict__ dst) {
    const size_t i = (size_t)(blockIdx.x * 256 + threadIdx.x) * 4;
    floatx4 v = *(const floatx4*)(src + i);
    union { bf16x4 s; __hip_bfloat16 h[4]; } u;
#pragma unroll
    for (int j = 0; j < 4; j++) u.h[j] = __float2bfloat16(v[j]);
    *(bf16x4*)(dst + i) = u.s;
}

__global__ __launch_bounds__(256) void transpose_cvt_kernel(
    const float* __restrict__ W, __hip_bfloat16* __restrict__ WT, int ld) {
    __shared__ __hip_bfloat16 tile[64][72];   // [k][n]
    const int tid = threadIdx.x;
    const int r = tid >> 2, c0 = (tid & 3) * 16;
    const int k0 = blockIdx.x * 64;
    const int n0 = blockIdx.y * 64;
    const float* src = W + (size_t)(k0 + r) * ld + n0 + c0;
    union { short8 v; __hip_bfloat16 h[8]; } a0, a1;
#pragma unroll
    for (int j = 0; j < 8; j++) {
        a0.h[j] = __float2bfloat16(src[j]);
        a1.h[j] = __float2bfloat16(src[8 + j]);
    }
    *(short8*)&tile[r][c0]     = a0.v;
    *(short8*)&tile[r][c0 + 8] = a1.v;
    __syncthreads();
    union { short8 v; __hip_bfloat16 h[8]; } u0, u1;
#pragma unroll
    for (int j = 0; j < 8; j++) {
        u0.h[j] = tile[c0 + j][r];
        u1.h[j] = tile[c0 + 8 + j][r];
    }
    __hip_bfloat16* dst = WT + (size_t)(n0 + r) * 1024 + k0 + c0;
    *(short8*)dst       = u0.v;
    *(short8*)(dst + 8) = u1.v;
}

__global__ __launch_bounds__(256) void transpose_t_kernel(
    const __hip_bfloat16* __restrict__ t,
    __hip_bfloat16* __restrict__ Tt) {
    __shared__ __hip_bfloat16 tile[64][72];
    const int tid = threadIdx.x;
    const int r = tid >> 2, c0 = (tid & 3) * 16;
    const int row0 = blockIdx.x * 64;
    const int col0 = blockIdx.y * 64;
    const __hip_bfloat16* src = t + (size_t)(row0 + r) * DIMM + col0 + c0;
    *(short8*)&tile[r][c0]     = *(const short8*)src;
    *(short8*)&tile[r][c0 + 8] = *(const short8*)(src + 8);
    __syncthreads();
    union { short8 v; __hip_bfloat16 h[8]; } u0, u1;
#pragma unroll
    for (int j = 0; j < 8; j++) {
        u0.h[j] = tile[c0 + j][r];
        u1.h[j] = tile[c0 + 8 + j][r];
    }
    __hip_bfloat16* dst = Tt + (size_t)(col0 + r) * ROWS + row0 + c0;
    *(short8*)dst       = u0.v;
    *(short8*)(dst + 8) = u1.v;
}

// ---------------------------------------------------------------------------
// bf16 GEMM v2: C = A @ BT^T (+bias). m97 recipe at 128Mx64N, BK=64:
// global_load_lds width-16 staging into linear LDS, double-buffered (48 KiB),
// one barrier per K-step, grid 512 = 2 blocks/CU (cross-block overlap of the
// vmcnt-drain barrier). 4 waves, each 64x32 = 4x2 16x16 frags.
// ---------------------------------------------------------------------------
template <typename CT>
__global__ __launch_bounds__(256) void gemm_bf_kernel(
    const __hip_bfloat16* __restrict__ A,
    const __hip_bfloat16* __restrict__ BT,
    const float* __restrict__ bias,   // may be null
    CT* __restrict__ C, int M, int N, int K) {
    __shared__ __align__(16) __hip_bfloat16 As[2][128][64];  // 32 KiB
    __shared__ __align__(16) __hip_bfloat16 Bs[2][64][64];   // 16 KiB

    const int tid  = threadIdx.x;
    const int lane = tid & 63, wid = tid >> 6;
    const int wm   = wid >> 1, wn = wid & 1;
    const int quad = lane >> 4, l15 = lane & 15;
    const int bm = blockIdx.y * 128, bn = blockIdx.x * 64;

    floatx4 acc[4][2];
#pragma unroll
    for (int r = 0; r < 4; r++)
#pragma unroll
        for (int c = 0; c < 2; c++) acc[r][c] = (floatx4){0.f, 0.f, 0.f, 0.f};

    // staging geometry: thread t covers LDS bytes j*4096 + t*16 of the tile.
    const int to    = tid << 4;            // 0..4080
    const int arow  = to >> 7;             // row within 32-row chunk
    const int acol  = (to & 127) >> 1;     // elem col 0..63
    const int wbase = to & ~1023;          // wave-uniform byte base in chunk

    auto stage = [&](int k0, int buf) {
#if HAVE_GLOAD
#pragma unroll
        for (int j = 0; j < 4; j++)        // A tile: 16 KiB = 4 calls
            gload16(A + (size_t)(bm + j * 32 + arow) * K + k0 + acol,
                    (char*)&As[buf][0][0] + j * 4096 + wbase);
#pragma unroll
        for (int j = 0; j < 2; j++)        // B tile: 8 KiB = 2 calls
            gload16(BT + (size_t)(bn + j * 32 + arow) * K + k0 + acol,
                    (char*)&Bs[buf][0][0] + j * 4096 + wbase);
#else
#pragma unroll
        for (int j = 0; j < 4; j++) {
            short8 v = *(const short8*)(A + (size_t)(bm + j * 32 + arow) * K + k0 + acol);
            *(short8*)((char*)&As[buf][0][0] + j * 4096 + to) = v;
        }
#pragma unroll
        for (int j = 0; j < 2; j++) {
            short8 v = *(const short8*)(BT + (size_t)(bn + j * 32 + arow) * K + k0 + acol);
            *(short8*)((char*)&Bs[buf][0][0] + j * 4096 + to) = v;
        }
#endif
    };

    stage(0, 0);
    __syncthreads();

    const int nk = K >> 6;
    for (int kb = 0; kb < nk; ++kb) {
        const int buf = kb & 1;
        if (kb + 1 < nk) stage((kb + 1) << 6, buf ^ 1);   // async, drains at barrier
#pragma unroll
        for (int ks = 0; ks < 2; ks++) {
            short8 af[4], bfr[2];
#pragma unroll
            for (int r = 0; r < 4; r++)
                af[r] = *(const short8*)&As[buf][wm * 64 + r * 16 + l15][ks * 32 + quad * 8];
#pragma unroll
            for (int c = 0; c < 2; c++)
                bfr[c] = *(const short8*)&Bs[buf][wn * 32 + c * 16 + l15][ks * 32 + quad * 8];
#pragma unroll
            for (int r = 0; r < 4; r++)
#pragma unroll
                for (int c = 0; c < 2; c++)
                    acc[r][c] = MFMA16(af[r], bfr[c], acc[r][c]);
        }
        __syncthreads();
    }

#pragma unroll
    for (int c = 0; c < 2; c++) {
        const int col = bn + wn * 32 + c * 16 + l15;
        const float bv = bias ? bias[col] : 0.f;
#pragma unroll
        for (int r = 0; r < 4; r++) {
            const int row0 = bm + wm * 64 + r * 16 + quad * 4;
#pragma unroll
            for (int i = 0; i < 4; i++) {
                const float v = acc[r][c][i] + bv;
                if constexpr (__is_same(CT, float))
                    C[(size_t)(row0 + i) * N + col] = v;
                else
                    C[(size_t)(row0 + i) * N + col] = __float2bfloat16(v);
            }
        }
    }
}

// ---------------------------------------------------------------------------
// Fallback GEMM (fp32 inputs, in-LDS transpose) — only if ws is tiny.
// ---------------------------------------------------------------------------
template <typename AT, typename CT>
__global__ __launch_bounds__(256) void gemm_fp_kernel(
    const AT* __restrict__ A, const float* __restrict__ B,
    const float* __restrict__ bias, CT* __restrict__ C,
    int M, int N, int K, int ldb) {
    __shared__ __align__(16) __hip_bfloat16 As[2][64][40];
    __shared__ __align__(16) __hip_bfloat16 Bs[2][128][40];
    const int tid = threadIdx.x;
    const int lane = tid & 63, wid = tid >> 6;
    const int wm = wid >> 1, wn = wid & 1;
    const int quad = lane >> 4, l15 = lane & 15;
    const int bm = blockIdx.y * 64, bn = blockIdx.x * 128;
    floatx4 acc[2][4];
#pragma unroll
    for (int r = 0; r < 2; r++)
#pragma unroll
        for (int c = 0; c < 4; c++) acc[r][c] = (floatx4){0.f, 0.f, 0.f, 0.f};
    const int a_lr = tid >> 2, a_lc = (tid & 3) * 8;
    const int b_kr = tid & 31, b_nc = (tid >> 5) * 16;
    floatx4 raf0, raf1; short8 rab; floatx4 rb[4];
    auto load_tile = [&](int k0) {
        const AT* pa = A + (size_t)(bm + a_lr) * K + k0 + a_lc;
        if constexpr (__is_same(AT, float)) {
            raf0 = *(const floatx4*)pa; raf1 = *(const floatx4*)(pa + 4);
        } else { rab = *(const short8*)pa; }
        const float* pb = B + (size_t)(k0 + b_kr) * ldb + bn + b_nc;
#pragma unroll
        for (int q = 0; q < 4; q++) rb[q] = *(const floatx4*)(pb + 4 * q);
    };
    auto store_tile = [&](int buf) {
        if constexpr (__is_same(AT, float)) {
            __align__(16) __hip_bfloat16 hh[8];
#pragma unroll
            for (int j = 0; j < 4; j++) {
                hh[j] = __float2bfloat16(raf0[j]); hh[4 + j] = __float2bfloat16(raf1[j]);
            }
            *(short8*)&As[buf][a_lr][a_lc] = *(short8*)&hh[0];
        } else { *(short8*)&As[buf][a_lr][a_lc] = rab; }
#pragma unroll
        for (int q = 0; q < 4; q++)
#pragma unroll
            for (int j = 0; j < 4; j++)
                Bs[buf][b_nc + 4 * q + j][b_kr] = __float2bfloat16(rb[q][j]);
    };
    load_tile(0); store_tile(0);
    if (K > 32) load_tile(32);
    __syncthreads();
    const int nk = K >> 5;
    for (int kb = 0; kb < nk; ++kb) {
        const int buf = kb & 1;
        short8 af[2], bf[4];
#pragma unroll
        for (int r = 0; r < 2; r++)
            af[r] = *(const short8*)&As[buf][wm * 32 + r * 16 + l15][quad * 8];
#pragma unroll
        for (int c = 0; c < 4; c++)
            bf[c] = *(const short8*)&Bs[buf][wn * 64 + c * 16 + l15][quad * 8];
#pragma unroll
        for (int r = 0; r < 2; r++)
#pragma unroll
            for (int c = 0; c < 4; c++)
                acc[r][c] = MFMA16(af[r], bf[c], acc[r][c]);
        if (kb + 1 < nk) store_tile(buf ^ 1);
        if (kb + 2 < nk) load_tile((kb + 2) << 5);
        __syncthreads();
    }
#pragma unroll
    for (int c = 0; c < 4; c++) {
        const int col = bn + wn * 64 + c * 16 + l15;
        const float bv = bias ? bias[col] : 0.f;
#pragma unroll
        for (int r = 0; r < 2; r++) {
            const int row0 = bm + wm * 32 + r * 16 + quad * 4;
#pragma unroll
            for (int i = 0; i < 4; i++) {
                const float v = acc[r][c][i] + bv;
                if constexpr (__is_same(CT, float)) C[(size_t)(row0 + i) * N + col] = v;
                else C[(size_t)(row0 + i) * N + col] = __float2bfloat16(v);
            }
        }
    }
}

// ---------------------------------------------------------------------------
// Causal flash attention v2: 128 Q rows/block (4 waves x 32 rows, 2 Q-frags
// per wave). Each K/V LDS read and each staged global byte now serves 2x the
// MFMA work vs the 64-row version -> LDS + HBM traffic per unit work halves.
// grid 512 = 2 blocks/CU (LDS 34 KiB), balanced qt pairing across the two
// grid halves so each CU gets 34 tile-units. S^T = K Q^T; P packs in-register
// to 16x16x16 A-frags; V^T staged from pre-transposed Tt. Compute-before-
// store, double-buffered K/V, one barrier/iter.
// ---------------------------------------------------------------------------
__global__ __launch_bounds__(256) void attn_kernel(
    const __hip_bfloat16* __restrict__ T,    // [4096][1024]
    const __hip_bfloat16* __restrict__ Tt,   // [1024][4096]
    __hip_bfloat16* __restrict__ O) {        // [4096][1024]
    __shared__ __align__(16) __hip_bfloat16 Ks[2][64][68];  // K rows [key][d]
    __shared__ __align__(16) __hip_bfloat16 Vt[2][64][68];  // V^T    [d][key]

    const int tid  = threadIdx.x;
    const int lane = tid & 63, wid = tid >> 6;
    const int quad = lane >> 4, l15 = lane & 15;

    // balanced decode over 512 blocks: CU i gets bx=i (qt=15-g) and bx=i+256
    // (qt=g) -> 34 tile-units per CU regardless of g.
    const int bx = blockIdx.x;
    const int half = bx >> 8, idx = bx & 255;
    const int g = idx & 7, h = (idx >> 3) & 15, b = idx >> 7;
    const int qt = half ? g : 15 - g;          // 0..15, 128-row q tile

    const size_t rowbase = (size_t)b * SEQ;
    const int hoff  = h * DHEAD;
    const int qrow0 = qt * 128;

    // Q fragments (B-operand of S^T): wave owns 32 q rows = 2 frags x K=64
    short8 qf[2][2];
#pragma unroll
    for (int qr = 0; qr < 2; qr++) {
        const __hip_bfloat16* qp =
            T + (rowbase + qrow0 + wid * 32 + qr * 16 + l15) * DIMM + hoff + quad * 8;
        qf[qr][0] = *(const short8*)qp;
        qf[qr][1] = *(const short8*)(qp + 32);
    }

    float l_lane[2] = {0.f, 0.f};
    floatx4 accO[2][4];
#pragma unroll
    for (int qr = 0; qr < 2; qr++)
#pragma unroll
        for (int dt = 0; dt < 4; dt++) accO[qr][dt] = (floatx4){0.f,0.f,0.f,0.f};

    // staging: 2 vector loads + 2 vector stores per thread per array
    const int sr = tid >> 2;           // 0..63
    const int sc = (tid & 3) * 16;     // 0,16,32,48

    short8 rK0, rK1, rV0, rV1;
    auto load_tile = [&](int kt) {
        const __hip_bfloat16* pK = T + (rowbase + kt * 64 + sr) * DIMM + hoff + sc;
        rK0 = *(const short8*)pK; rK1 = *(const short8*)(pK + 8);
        const __hip_bfloat16* pV =
            Tt + (size_t)(hoff + sr) * ROWS + rowbase + kt * 64 + sc;
        rV0 = *(const short8*)pV; rV1 = *(const short8*)(pV + 8);
    };
    auto store_tile = [&](int buf) {
        *(short8*)&Ks[buf][sr][sc]     = rK0;
        *(short8*)&Ks[buf][sr][sc + 8] = rK1;
        *(short8*)&Vt[buf][sr][sc]     = rV0;
        *(short8*)&Vt[buf][sr][sc + 8] = rV1;
    };

    const int last = 2 * qt + 1;       // diagonal spans 2 kv-tiles
    load_tile(0);
    store_tile(0);
    load_tile(1);                      // last >= 1 always
    __syncthreads();

    for (int kt = 0; kt <= last; ++kt) {
        const int buf = kt & 1;

        // ---- S^T = K Q^T for both q-frags; K-frags read once, used twice ----
        bf16x4 pk[2][4];
        const bool need_mask = (kt >= 2 * qt);
#pragma unroll
        for (int c = 0; c < 4; c++) {
            short8 k0 = *(const short8*)&Ks[buf][c * 16 + l15][quad * 8];
            short8 k1 = *(const short8*)&Ks[buf][c * 16 + l15][32 + quad * 8];
            floatx4 s[2];
            s[0] = (floatx4){0.f,0.f,0.f,0.f};
            s[1] = (floatx4){0.f,0.f,0.f,0.f};
            s[0] = MFMA16(k0, qf[0][0], s[0]);
            s[1] = MFMA16(k0, qf[1][0], s[1]);
            s[0] = MFMA16(k1, qf[0][1], s[0]);
            s[1] = MFMA16(k1, qf[1][1], s[1]);

            // p = exp2(s*K1+K2) masked; pack to 16x16x16 A-frags in-register
#pragma unroll
            for (int qr = 0; qr < 2; qr++) {
                union { bf16x4 v; __hip_bfloat16 hh[4]; } u;
                float sum = 0.f;
                const int qrow = qrow0 + wid * 32 + qr * 16 + l15;
#pragma unroll
                for (int i = 0; i < 4; i++) {
                    float v = exp2f(fmaf(s[qr][i], K1, K2));
                    if (need_mask) {
                        const int key = kt * 64 + c * 16 + quad * 4 + i;
                        if (key > qrow) v = 0.f;
                    }
                    sum += v;
                    u.hh[i] = __float2bfloat16(v);
                }
                l_lane[qr] += sum;
                pk[qr][c] = u.v;
            }
        }

        // ---- O += P V : V-frags read once, used for both q-frags ----
        __builtin_amdgcn_s_setprio(1);
#pragma unroll
        for (int c = 0; c < 4; c++)
#pragma unroll
            for (int dt = 0; dt < 4; dt++) {
                bf16x4 vb = *(const bf16x4*)&Vt[buf][dt * 16 + l15][c * 16 + quad * 4];
                accO[0][dt] = MFMA_PV(pk[0][c], vb, accO[0][dt]);
                accO[1][dt] = MFMA_PV(pk[1][c], vb, accO[1][dt]);
            }
        __builtin_amdgcn_s_setprio(0);

        // ---- then stage next tile + prefetch ----
        if (kt < last)      store_tile(buf ^ 1);
        if (kt + 2 <= last) load_tile(kt + 2);
        __syncthreads();
    }

    // l per q=l15: reduce across quads, redistribute to C-layout rows
#pragma unroll
    for (int qr = 0; qr < 2; qr++) {
        l_lane[qr] += __shfl_xor(l_lane[qr], 16);
        l_lane[qr] += __shfl_xor(l_lane[qr], 32);
    }
    float inv[2][4];
#pragma unroll
    for (int qr = 0; qr < 2; qr++)
#pragma unroll
        for (int i = 0; i < 4; i++)
            inv[qr][i] = 1.f / __shfl(l_lane[qr], quad * 4 + i, 64);
#pragma unroll
    for (int qr = 0; qr < 2; qr++)
#pragma unroll
        for (int dt = 0; dt < 4; dt++)
#pragma unroll
            for (int i = 0; i < 4; i++) {
                const size_t row = rowbase + qrow0 + wid * 32 + qr * 16 + quad * 4 + i;
                O[row * DIMM + hoff + dt * 16 + l15] =
                    __float2bfloat16(accO[qr][dt][i] * inv[qr][i]);
            }
}

// ---------------------------------------------------------------------------
extern "C" void kernel_launch(void* const* d_in, const int* in_sizes, int n_in,
                              void* d_out, int out_size, void* d_ws, size_t ws_size,
                              hipStream_t stream) {
    const float* x     = (const float*)d_in[0];  // [2,2048,1024] fp32
    const float* w_qkv = (const float*)d_in[1];  // [1024,3072]   fp32
    const float* w_out = (const float*)d_in[2];  // [1024,1024]   fp32
    const float* b_out = (const float*)d_in[3];  // [1024]        fp32
    float* out = (float*)d_out;                  // [2,2048,1024] fp32 (16 MiB)

    // t (bf16) in d_out[0,8MiB); Tt in d_out[8,16MiB). Dead before final GEMM.
    __hip_bfloat16* t  = (__hip_bfloat16*)d_out;
    __hip_bfloat16* Tt = (__hip_bfloat16*)((char*)d_out + (8u << 20));
    char* ws = (char*)d_ws;
    __hip_bfloat16* ob = (__hip_bfloat16*)ws;    // 8 MiB, both paths

    if (ws_size >= (size_t)(20u << 20)) {
        __hip_bfloat16* xb  = (__hip_bfloat16*)(ws + (8u  << 20)); // 8 MiB
        __hip_bfloat16* w1t = (__hip_bfloat16*)(ws + (16u << 20)); // 2 MiB
        __hip_bfloat16* w2t = (__hip_bfloat16*)(ws + (18u << 20)); // 2 MiB

        cvt_bf16_kernel<<<4096, 256, 0, stream>>>(x, xb);
        transpose_cvt_kernel<<<dim3(16, 16), 256, 0, stream>>>(w_qkv, w1t, 3 * DIMM);
        transpose_cvt_kernel<<<dim3(16, 16), 256, 0, stream>>>(w_out, w2t, DIMM);

        gemm_bf_kernel<__hip_bfloat16><<<dim3(16, 32), 256, 0, stream>>>(
            xb, w1t, nullptr, t, ROWS, DIMM, DIMM);
        transpose_t_kernel<<<dim3(64, 16), 256, 0, stream>>>(t, Tt);
        attn_kernel<<<dim3(512), 256, 0, stream>>>(t, Tt, ob);
        gemm_bf_kernel<float><<<dim3(16, 32), 256, 0, stream>>>(
            ob, w2t, b_out, out, ROWS, DIMM, DIMM);
    } else {
        gemm_fp_kernel<float, __hip_bfloat16><<<dim3(8, 64), 256, 0, stream>>>(
            x, w_qkv, nullptr, t, ROWS, DIMM, DIMM, 3 * DIMM);
        transpose_t_kernel<<<dim3(64, 16), 256, 0, stream>>>(t, Tt);
        attn_kernel<<<dim3(512), 256, 0, stream>>>(t, Tt, ob);
        gemm_fp_kernel<__hip_bfloat16, float><<<dim3(8, 64), 256, 0, stream>>>(
            ob, w_out, b_out, out, ROWS, DIMM, DIMM, DIMM);
    }
}